// Round 20
// baseline (297.334 us; speedup 1.0000x reference)
//
#include <hip/hip_runtime.h>
#include <hip/hip_bf16.h>

// Problem constants
#define B_ 2
#define H_ 16
#define T_ 2048
#define D_ 64
#define ED_ 1024
// SCALING = 1/sqrt(64) = 0.125

typedef __attribute__((ext_vector_type(8))) short bf16x8;
typedef __attribute__((ext_vector_type(4))) short bf16x4;
typedef __attribute__((ext_vector_type(4))) float f32x4;

// async global->LDS, 16B per lane. LDS dest must be wave-uniform base + lane*16 (linear).
__device__ __forceinline__ void gload16(const void* g, void* l) {
  __builtin_amdgcn_global_load_lds(
      (const __attribute__((address_space(1))) unsigned int*)(uintptr_t)g,
      (__attribute__((address_space(3))) unsigned int*)(uintptr_t)l,
      16, 0, 0);
}

// NT (non-temporal) variant for COLD stream-once READS only (bias input).
__device__ __forceinline__ void gload16nt(const void* g, void* l) {
  __builtin_amdgcn_global_load_lds(
      (const __attribute__((address_space(1))) unsigned int*)(uintptr_t)g,
      (__attribute__((address_space(3))) unsigned int*)(uintptr_t)l,
      16, 0, 2);
}

__device__ __forceinline__ float b2f(short s) {
  unsigned int u = ((unsigned int)(unsigned short)s) << 16;
  return __builtin_bit_cast(float, u);
}
__device__ __forceinline__ short f2b(float v) {
  return __builtin_bit_cast(short, __float2bfloat16(v));
}

// ---------------- kernel 1: f32 -> bf16 conversion (query + 4 weight mats) ----------------
__global__ __launch_bounds__(256) void convert_f32_bf16(
    const float* __restrict__ x, const float* __restrict__ wq, const float* __restrict__ wk,
    const float* __restrict__ wv, const float* __restrict__ wo,
    __hip_bfloat16* __restrict__ xb, __hip_bfloat16* __restrict__ wqb,
    __hip_bfloat16* __restrict__ wkb, __hip_bfloat16* __restrict__ wvb,
    __hip_bfloat16* __restrict__ wob)
{
  int id = blockIdx.x * 256 + threadIdx.x;     // 2,097,152 threads
  size_t e0 = (size_t)id * 4;
  const float* src; __hip_bfloat16* dst; size_t off;
  if (e0 < 4194304) { src = x; dst = xb; off = e0; }
  else {
    size_t r = e0 - 4194304;
    int wsel = (int)(r >> 20);
    off = r & 1048575;
    src = (wsel == 0) ? wq : (wsel == 1) ? wk : (wsel == 2) ? wv : wo;
    dst = (wsel == 0) ? wqb : (wsel == 1) ? wkb : (wsel == 2) ? wvb : wob;
  }
  float4 v = *(const float4*)(src + off);
  __hip_bfloat16 o[4];
  o[0] = __float2bfloat16(v.x); o[1] = __float2bfloat16(v.y);
  o[2] = __float2bfloat16(v.z); o[3] = __float2bfloat16(v.w);
  *(ushort4*)(dst + off) = *(ushort4*)o;   // 8B store
}

// ---------------- kernel 2/5: GEMM  C[M,N] = A[M,K] * Bw[N,K]^T, M=4096 N=1024 K=1024 ----
struct GemmP {
  const __hip_bfloat16* A;
  const __hip_bfloat16* Bw[3];
  const float* bias[3];
  void* out[3];
  float scale[3];
  int mode[3];   // 0: bf16 row-major, 1: f32 row-major, 2: bf16 transposed [b,h,d,t]
};

__global__ __launch_bounds__(256, 3) void gemm_nt(GemmP p)
{
  __shared__ __hip_bfloat16 As[128 * 64];   // 16 KB
  __shared__ __hip_bfloat16 Bs[128 * 64];   // 16 KB
  const int tid = threadIdx.x;
  const int z = blockIdx.z;
  const __hip_bfloat16* A = p.A;
  const __hip_bfloat16* Bw = p.Bw[z];
  const int bm0 = blockIdx.x * 128, bn0 = blockIdx.y * 128;
  const int l = tid & 63, w = tid >> 6;
  const int wr = w >> 1, wc = w & 1;
  const int lhi = l >> 4, llo = l & 15;
  const int swl = (llo & 7) << 3;           // read-side XOR (row&7 == llo&7 for frag rows)

  f32x4 acc[4][4];
#pragma unroll
  for (int m = 0; m < 4; ++m)
#pragma unroll
    for (int n = 0; n < 4; ++n) acc[m][n] = (f32x4){0.f, 0.f, 0.f, 0.f};

  for (int kt = 0; kt < 1024; kt += 64) {
#pragma unroll
    for (int j = 0; j < 4; ++j) {
      int off = j * 2048 + tid * 8;        // element offset; linear LDS (lane*16B)
      int row = off >> 6;                  // /64
      int col = off & 63;
      int cs = col ^ ((row & 7) << 3);     // inverse-swizzled global source
      gload16(&A[(size_t)(bm0 + row) * 1024 + kt + cs], &As[off]);
      gload16(&Bw[(size_t)(bn0 + row) * 1024 + kt + cs], &Bs[off]);
    }
    __syncthreads();
#pragma unroll
    for (int kk = 0; kk < 2; ++kk) {
      bf16x8 af[4], bf[4];
#pragma unroll
      for (int m = 0; m < 4; ++m)
        af[m] = *(const bf16x8*)&As[(wr * 64 + m * 16 + llo) * 64 + ((kk * 32 + lhi * 8) ^ swl)];
#pragma unroll
      for (int n = 0; n < 4; ++n)
        bf[n] = *(const bf16x8*)&Bs[(wc * 64 + n * 16 + llo) * 64 + ((kk * 32 + lhi * 8) ^ swl)];
#pragma unroll
      for (int m = 0; m < 4; ++m)
#pragma unroll
        for (int n = 0; n < 4; ++n)
          acc[m][n] = __builtin_amdgcn_mfma_f32_16x16x32_bf16(af[m], bf[n], acc[m][n], 0, 0, 0);
    }
    __syncthreads();
  }

  // epilogue: C/D layout col=lane&15, row=(lane>>4)*4+reg (m89/m91 verified)
  const float* bias = p.bias[z];
  const float scale = p.scale[z];
  const int mode = p.mode[z];
  float bv[4];
#pragma unroll
  for (int n = 0; n < 4; ++n) bv[n] = bias[bn0 + wc * 64 + n * 16 + llo];
#pragma unroll
  for (int m = 0; m < 4; ++m) {
    int rowb = bm0 + wr * 64 + m * 16 + lhi * 4;
#pragma unroll
    for (int n = 0; n < 4; ++n) {
      int col = bn0 + wc * 64 + n * 16 + llo;
#pragma unroll
      for (int r = 0; r < 4; ++r) {
        float v = (acc[m][n][r] + bv[n]) * scale;
        int row = rowb + r;
        if (mode == 0) {
          ((__hip_bfloat16*)p.out[z])[(size_t)row * 1024 + col] = __float2bfloat16(v);
        } else if (mode == 1) {
          ((float*)p.out[z])[(size_t)row * 1024 + col] = v;
        } else {
          int bb = row >> 11, t = row & 2047;     // row = b*2048+t
          int hh = col >> 6, d = col & 63;        // col = h*64+d
          ((__hip_bfloat16*)p.out[z])[((size_t)((bb * 16 + hh) * 64 + d)) * 2048 + t] =
              __float2bfloat16(v);
        }
      }
    }
  }
}

// ---------------- kernel 3: attention (SBLK=32: counted-vmcnt + 4 blocks/CU) ----------
// grid (32 qt, 16 h, 2 b), 256 thr = 4 waves; wave owns 16 q-rows; s-chunks of 32 (64 it).
// Swapped QK^T: sa[f][r] = S[t=tl][s = s0 + f*16 + lhi*4 + r], f in {0,1}.
// LDS = Ks 2x4 + Vs 2x4 + bS 2x8 + Ps 4 = 36 KB -> 4 blocks/CU (launch_bounds(256,4)).
// Swizzles: Ks rows 128B -> elem XOR (row&7)<<3 (as before). Vs/Ps rows 64B ->
// natural 2-way (free, m136), linear. bS rows = 8x16B slots -> slot ^= row&7
// (write: pre-swizzled global source; read: same XOR).
// Pipeline (R14-verified): STAGE(it+1) -> vmcnt(6) -> s_barrier -> compute ->
// lgkmcnt(0) -> s_barrier.  vmcnt(6) = 4 prefetch + 2 prev E-stores. Tail vmcnt(2).
// Cache policy: bias NT-read; E stored normally; setprio around MFMA clusters.
__global__ __launch_bounds__(256, 4) void attn_fwd(
    const __hip_bfloat16* __restrict__ qb,   // [B*T,1024] pre-scaled q
    const __hip_bfloat16* __restrict__ kb,   // [B*T,1024]
    const __hip_bfloat16* __restrict__ vT,   // [B*H*64, 2048]  (v transposed)
    const float* __restrict__ bias,          // [B,H,T,T]
    unsigned char* __restrict__ Ebuf,        // [B,H,T,T] fp8 e4m3 of exp(s)/16
    float* __restrict__ invl,                // [B,H,T] 1/l
    __hip_bfloat16* __restrict__ attn)       // [B*T,1024]
{
  __shared__ __hip_bfloat16 Ks[2][32 * 64];  // 8 KB  [s=32][d=64], swizzled (row&7)<<3
  __shared__ __hip_bfloat16 Vs[2][64 * 32];  // 8 KB  [d=64][s=32], linear
  __shared__ float          bS[2][64 * 32];  // 16 KB [t=64][s=32], slot-swizzled
  __shared__ __hip_bfloat16 Ps[64 * 32];     // 4 KB  [t=64][s=32], linear
  const int tid = threadIdx.x;
  const int l = tid & 63, w = tid >> 6;
  const int lhi = l >> 4, llo = l & 15;
  const int swl = (llo & 7) << 3;
  const int qt = blockIdx.x, h = blockIdx.y, b = blockIdx.z;
  const int t0 = qt * 64;
  const int tl = w * 16 + llo;               // this lane's local q-row (replicated x4 lhi)
  const __hip_bfloat16* kbase = kb + ((size_t)b * 2048) * 1024 + h * 64;
  const __hip_bfloat16* vbase = vT + ((size_t)((b * 16 + h) * 64)) * 2048;
  const float* bbase = bias + (((size_t)(b * 16 + h)) * 2048 + t0) * 2048;
  unsigned char* erow = Ebuf + (((size_t)(b * 16 + h)) * 2048 + t0 + tl) * 2048;

  // Q fragments straight from global (one-time; drained by prologue vmcnt(0))
  bf16x8 qa[2];
#pragma unroll
  for (int kk = 0; kk < 2; ++kk)
    qa[kk] = *(const bf16x8*)&qb[((size_t)(b * 2048 + t0 + tl)) * 1024 +
                                 h * 64 + kk * 32 + lhi * 8];

  f32x4 acc_o[4];
#pragma unroll
  for (int f = 0; f < 4; ++f) acc_o[f] = (f32x4){0.f, 0.f, 0.f, 0.f};
  float lrun = 0.f;

  // 4 gload16 per thread per STAGE: 1 K + 1 V (cached) + 2 bias (NT)
#define STAGE(BUF, S0)                                                         \
  do {                                                                         \
    {                                                                          \
      int off = tid * 8;                   /* Ks: 32x64 elems */               \
      int row = off >> 6, col = off & 63;                                      \
      int cs = col ^ ((row & 7) << 3);                                         \
      gload16(&kbase[(size_t)((S0) + row) * 1024 + cs], &Ks[BUF][off]);        \
    }                                                                          \
    {                                                                          \
      int off = tid * 8;                   /* Vs: 64x32 elems, linear */       \
      int row = off >> 5, col = off & 31;                                      \
      gload16(&vbase[(size_t)row * 2048 + (S0) + col], &Vs[BUF][off]);         \
    }                                                                          \
    _Pragma("unroll") for (int j2 = 0; j2 < 2; ++j2) {                         \
      int off = j2 * 1024 + tid * 4;       /* bS: 64x32 f32, slot-swizzled */  \
      int row = off >> 5, col = off & 31;                                      \
      int cs = (((col >> 2) ^ (row & 7)) << 2);                                \
      gload16nt(&bbase[(size_t)row * 2048 + (S0) + cs], &bS[BUF][off]);        \
    }                                                                          \
  } while (0)

  // prologue: stage tile 0, one-time full drain (also covers qa), barrier
  STAGE(0, 0);
  asm volatile("s_waitcnt vmcnt(0)" ::: "memory");
  __builtin_amdgcn_sched_barrier(0);
  __builtin_amdgcn_s_barrier();

  for (int it = 0; it < 64; ++it) {
    const int s0 = it * 32;
    const int cur = it & 1;

    // ---- issue prefetch for it+1 (stays in flight across the barrier) ----
    if (it < 63) {
      STAGE(cur ^ 1, s0 + 32);
      // newer-than-tile-it ops: 4 prefetch + 2 prev-iter E-stores -> allow 6.
      asm volatile("s_waitcnt vmcnt(6)" ::: "memory");
    } else {
      asm volatile("s_waitcnt vmcnt(2)" ::: "memory");
    }
    __builtin_amdgcn_sched_barrier(0);
    __builtin_amdgcn_s_barrier();   // all waves verified their tile-it loads landed

    // ---- S^T = mfma(K, Q): sa[f][r] = S[t=tl][s = s0 + f*16 + lhi*4 + r] ----
    f32x4 sa[2];
#pragma unroll
    for (int f = 0; f < 2; ++f) sa[f] = (f32x4){0.f, 0.f, 0.f, 0.f};
    __builtin_amdgcn_s_setprio(1);
#pragma unroll
    for (int kk = 0; kk < 2; ++kk) {
#pragma unroll
      for (int f = 0; f < 2; ++f) {
        bf16x8 kf = *(const bf16x8*)&Ks[cur][(f * 16 + llo) * 64 +
                                            ((kk * 32 + lhi * 8) ^ swl)];
        sa[f] = __builtin_amdgcn_mfma_f32_16x16x32_bf16(kf, qa[kk], sa[f], 0, 0, 0);
      }
    }
    __builtin_amdgcn_s_setprio(0);
    // ---- bias (b128 LDS read, slot-deswizzled) + exp; Ps write b64; E pack ----
    float rsum = 0.f;
#pragma unroll
    for (int f = 0; f < 2; ++f) {
      int slot = (f * 4 + lhi) ^ (tl & 7);
      f32x4 bb = *(const f32x4*)&bS[cur][tl * 32 + (slot << 2)];
      float ev[4];
#pragma unroll
      for (int r = 0; r < 4; ++r) {
        ev[r] = __expf(sa[f][r] + bb[r]);
        rsum += ev[r];
      }
      bf16x4 pw;
      pw[0] = f2b(ev[0]); pw[1] = f2b(ev[1]);
      pw[2] = f2b(ev[2]); pw[3] = f2b(ev[3]);
      *(bf16x4*)&Ps[tl * 32 + f * 16 + lhi * 4] = pw;
      int e01 = __builtin_amdgcn_cvt_pk_fp8_f32(ev[0] * 0.0625f, ev[1] * 0.0625f, 0, 0);
      int e = __builtin_amdgcn_cvt_pk_fp8_f32(ev[2] * 0.0625f, ev[3] * 0.0625f, e01, 1);
      *(unsigned int*)&erow[s0 + f * 16 + lhi * 4] = (unsigned int)e;
    }
    // ---- row-sum: row tl is split over the 4 lhi-lanes sharing llo ----
    rsum += __shfl_xor(rsum, 16);
    rsum += __shfl_xor(rsum, 32);
    lrun += rsum;
    // ---- PV: acc_o += P @ V  (k = s = 32 -> single mfma per d-frag) ----
    __builtin_amdgcn_s_setprio(1);
    {
      bf16x8 pa = *(const bf16x8*)&Ps[tl * 32 + lhi * 8];
#pragma unroll
      for (int f = 0; f < 4; ++f) {
        bf16x8 vf = *(const bf16x8*)&Vs[cur][(f * 16 + llo) * 32 + lhi * 8];
        acc_o[f] = __builtin_amdgcn_mfma_f32_16x16x32_bf16(pa, vf, acc_o[f], 0, 0, 0);
      }
    }
    __builtin_amdgcn_s_setprio(0);
    // ---- buffer-reuse fence: LDS reads done, then barrier (NO vmem drain) ----
    asm volatile("s_waitcnt lgkmcnt(0)" ::: "memory");
    __builtin_amdgcn_sched_barrier(0);
    __builtin_amdgcn_s_barrier();
  }
#undef STAGE

  // lane holds 1/l for row tl (replicated over lhi); output rows need lhi*4+r
  float invs = 1.f / lrun;
  float inv4[4];
#pragma unroll
  for (int r = 0; r < 4; ++r) inv4[r] = __shfl(invs, lhi * 4 + r);
#pragma unroll
  for (int f = 0; f < 4; ++f) {
    int d = f * 16 + llo;
#pragma unroll
    for (int r = 0; r < 4; ++r) {
      int t = t0 + w * 16 + lhi * 4 + r;
      attn[((size_t)(b * 2048 + t)) * 1024 + h * 64 + d] =
          __float2bfloat16(acc_o[f][r] * inv4[r]);
    }
  }
  if (l < 16)
    invl[((size_t)(b * 16 + h)) * 2048 + t0 + w * 16 + l] = invs;
}

// ---------------- kernel 4: avg_weights = sum_h E * inv_l  (the /16 is absorbed) -------
__global__ __launch_bounds__(256) void avgw_k(
    const unsigned char* __restrict__ Ebuf, const float* __restrict__ invl,
    float* __restrict__ outw)
{
  int c = blockIdx.x * 256 + threadIdx.x;   // 0..524287 : (b, t, 16-wide s chunk)
  int b = c >> 18;
  int rem = c & 262143;
  int t = rem >> 7;
  int s0 = (rem & 127) << 4;
  float acc[16];
#pragma unroll
  for (int i = 0; i < 16; ++i) acc[i] = 0.f;
#pragma unroll
  for (int hh = 0; hh < 16; ++hh) {
    float inv = invl[((size_t)(b * 16 + hh)) * 2048 + t];
    uint4 evv = *(const uint4*)&Ebuf[(((size_t)(b * 16 + hh)) * 2048 + t) * 2048 + s0];
    unsigned int dw[4] = {evv.x, evv.y, evv.z, evv.w};
#pragma unroll
    for (int q = 0; q < 4; ++q) {
      acc[q * 4 + 0] += __builtin_amdgcn_cvt_f32_fp8(dw[q], 0) * inv;
      acc[q * 4 + 1] += __builtin_amdgcn_cvt_f32_fp8(dw[q], 1) * inv;
      acc[q * 4 + 2] += __builtin_amdgcn_cvt_f32_fp8(dw[q], 2) * inv;
      acc[q * 4 + 3] += __builtin_amdgcn_cvt_f32_fp8(dw[q], 3) * inv;
    }
  }
  float* o = outw + ((size_t)(b * 2048 + t)) * 2048 + s0;
#pragma unroll
  for (int q = 0; q < 4; ++q)
    *(float4*)(o + q * 4) = make_float4(acc[q * 4], acc[q * 4 + 1], acc[q * 4 + 2], acc[q * 4 + 3]);
}

// ---------------- launch ----------------
extern "C" void kernel_launch(void* const* d_in, const int* in_sizes, int n_in,
                              void* d_out, int out_size, void* d_ws, size_t ws_size,
                              hipStream_t stream) {
  const float* query     = (const float*)d_in[0];
  // d_in[1] (key) and d_in[2] (value) are ignored: reference uses query for all.
  const float* attn_bias = (const float*)d_in[3];
  const float* Wq = (const float*)d_in[4];
  const float* bq = (const float*)d_in[5];
  const float* Wk = (const float*)d_in[6];
  const float* bk = (const float*)d_in[7];
  const float* Wv = (const float*)d_in[8];
  const float* bv = (const float*)d_in[9];
  const float* Wo = (const float*)d_in[10];
  const float* bo = (const float*)d_in[11];
  float* out = (float*)d_out;               // [0,4194304) proj-out, then [.. ) avg weights

  char* ws = (char*)d_ws;                   // ~185 MB total
  __hip_bfloat16* xb   = (__hip_bfloat16*)(ws + 0);
  __hip_bfloat16* wqb  = (__hip_bfloat16*)(ws + 8388608);
  __hip_bfloat16* wkb  = (__hip_bfloat16*)(ws + 10485760);
  __hip_bfloat16* wvb  = (__hip_bfloat16*)(ws + 12582912);
  __hip_bfloat16* wob  = (__hip_bfloat16*)(ws + 14680064);
  __hip_bfloat16* qbf  = (__hip_bfloat16*)(ws + 16777216);
  __hip_bfloat16* kbf  = (__hip_bfloat16*)(ws + 25165824);
  __hip_bfloat16* vTb  = (__hip_bfloat16*)(ws + 33554432);
  __hip_bfloat16* atnb = (__hip_bfloat16*)(ws + 41943040);
  float*          linv = (float*)(ws + 50331648);
  unsigned char*  Ebuf = (unsigned char*)(ws + 50593792);

  convert_f32_bf16<<<8192, 256, 0, stream>>>(query, Wq, Wk, Wv, Wo, xb, wqb, wkb, wvb, wob);

  GemmP gp{};
  gp.A = xb;
  gp.Bw[0] = wqb; gp.Bw[1] = wkb; gp.Bw[2] = wvb;
  gp.bias[0] = bq; gp.bias[1] = bk; gp.bias[2] = bv;
  gp.out[0] = qbf; gp.out[1] = kbf; gp.out[2] = vTb;
  gp.scale[0] = 0.125f; gp.scale[1] = 1.f; gp.scale[2] = 1.f;
  gp.mode[0] = 0; gp.mode[1] = 0; gp.mode[2] = 2;
  gemm_nt<<<dim3(32, 8, 3), 256, 0, stream>>>(gp);

  attn_fwd<<<dim3(32, 16, 2), 256, 0, stream>>>(qbf, kbf, vTb, attn_bias, Ebuf, linv, atnb);

  avgw_k<<<2048, 256, 0, stream>>>(Ebuf, linv, out + 4194304);

  GemmP go{};
  go.A = atnb;
  go.Bw[0] = wob; go.bias[0] = bo; go.out[0] = out;
  go.scale[0] = 1.f; go.mode[0] = 1;
  gemm_nt<<<dim3(32, 8, 1), 256, 0, stream>>>(go);
}

// Round 21
// 260.839 us; speedup vs baseline: 1.1399x; 1.1399x over previous
//
#include <hip/hip_runtime.h>
#include <hip/hip_bf16.h>

// Problem constants
#define B_ 2
#define H_ 16
#define T_ 2048
#define D_ 64
#define ED_ 1024
// SCALING = 1/sqrt(64) = 0.125

typedef __attribute__((ext_vector_type(8))) short bf16x8;
typedef __attribute__((ext_vector_type(4))) short bf16x4;
typedef __attribute__((ext_vector_type(4))) float f32x4;

// async global->LDS, 16B per lane. LDS dest must be wave-uniform base + lane*16 (linear).
__device__ __forceinline__ void gload16(const void* g, void* l) {
  __builtin_amdgcn_global_load_lds(
      (const __attribute__((address_space(1))) unsigned int*)(uintptr_t)g,
      (__attribute__((address_space(3))) unsigned int*)(uintptr_t)l,
      16, 0, 0);
}

// NT (non-temporal) variant for COLD stream-once READS only (bias input):
// keeps the 32x-reused K/V working set in L2. Do NOT use NT for stores
// (R16: partial-line streaming doubled WRITE_SIZE) or for just-produced
// intermediates (R17: bypasses their L2-resident tail).
__device__ __forceinline__ void gload16nt(const void* g, void* l) {
  __builtin_amdgcn_global_load_lds(
      (const __attribute__((address_space(1))) unsigned int*)(uintptr_t)g,
      (__attribute__((address_space(3))) unsigned int*)(uintptr_t)l,
      16, 0, 2);
}

__device__ __forceinline__ float b2f(short s) {
  unsigned int u = ((unsigned int)(unsigned short)s) << 16;
  return __builtin_bit_cast(float, u);
}
__device__ __forceinline__ short f2b(float v) {
  return __builtin_bit_cast(short, __float2bfloat16(v));
}

// ---------------- kernel 1: f32 -> bf16 conversion (query + 4 weight mats) ----------------
__global__ __launch_bounds__(256) void convert_f32_bf16(
    const float* __restrict__ x, const float* __restrict__ wq, const float* __restrict__ wk,
    const float* __restrict__ wv, const float* __restrict__ wo,
    __hip_bfloat16* __restrict__ xb, __hip_bfloat16* __restrict__ wqb,
    __hip_bfloat16* __restrict__ wkb, __hip_bfloat16* __restrict__ wvb,
    __hip_bfloat16* __restrict__ wob)
{
  int id = blockIdx.x * 256 + threadIdx.x;     // 2,097,152 threads
  size_t e0 = (size_t)id * 4;
  const float* src; __hip_bfloat16* dst; size_t off;
  if (e0 < 4194304) { src = x; dst = xb; off = e0; }
  else {
    size_t r = e0 - 4194304;
    int wsel = (int)(r >> 20);
    off = r & 1048575;
    src = (wsel == 0) ? wq : (wsel == 1) ? wk : (wsel == 2) ? wv : wo;
    dst = (wsel == 0) ? wqb : (wsel == 1) ? wkb : (wsel == 2) ? wvb : wob;
  }
  float4 v = *(const float4*)(src + off);
  __hip_bfloat16 o[4];
  o[0] = __float2bfloat16(v.x); o[1] = __float2bfloat16(v.y);
  o[2] = __float2bfloat16(v.z); o[3] = __float2bfloat16(v.w);
  *(ushort4*)(dst + off) = *(ushort4*)o;   // 8B store
}

// ---------------- kernel 2/5: GEMM  C[M,N] = A[M,K] * Bw[N,K]^T, M=4096 N=1024 K=1024 ----
// 128x128 tile, BK=64, 4 waves (2x2), each wave 64x64 = 4x4 frags of 16x16x32 bf16 MFMA.
// LDS tiles XOR-swizzled (elem col ^= (row&7)<<3) via pre-swizzled gload16 SOURCE (m173).
struct GemmP {
  const __hip_bfloat16* A;
  const __hip_bfloat16* Bw[3];
  const float* bias[3];
  void* out[3];
  float scale[3];
  int mode[3];   // 0: bf16 row-major, 1: f32 row-major, 2: bf16 transposed [b,h,d,t]
};

__global__ __launch_bounds__(256, 3) void gemm_nt(GemmP p)
{
  __shared__ __hip_bfloat16 As[128 * 64];   // 16 KB
  __shared__ __hip_bfloat16 Bs[128 * 64];   // 16 KB
  const int tid = threadIdx.x;
  const int z = blockIdx.z;
  const __hip_bfloat16* A = p.A;
  const __hip_bfloat16* Bw = p.Bw[z];
  const int bm0 = blockIdx.x * 128, bn0 = blockIdx.y * 128;
  const int l = tid & 63, w = tid >> 6;
  const int wr = w >> 1, wc = w & 1;
  const int lhi = l >> 4, llo = l & 15;
  const int swl = (llo & 7) << 3;           // read-side XOR (row&7 == llo&7 for frag rows)

  f32x4 acc[4][4];
#pragma unroll
  for (int m = 0; m < 4; ++m)
#pragma unroll
    for (int n = 0; n < 4; ++n) acc[m][n] = (f32x4){0.f, 0.f, 0.f, 0.f};

  for (int kt = 0; kt < 1024; kt += 64) {
#pragma unroll
    for (int j = 0; j < 4; ++j) {
      int off = j * 2048 + tid * 8;        // element offset; linear LDS (lane*16B)
      int row = off >> 6;                  // /64
      int col = off & 63;
      int cs = col ^ ((row & 7) << 3);     // inverse-swizzled global source
      gload16(&A[(size_t)(bm0 + row) * 1024 + kt + cs], &As[off]);
      gload16(&Bw[(size_t)(bn0 + row) * 1024 + kt + cs], &Bs[off]);
    }
    __syncthreads();
#pragma unroll
    for (int kk = 0; kk < 2; ++kk) {
      bf16x8 af[4], bf[4];
#pragma unroll
      for (int m = 0; m < 4; ++m)
        af[m] = *(const bf16x8*)&As[(wr * 64 + m * 16 + llo) * 64 + ((kk * 32 + lhi * 8) ^ swl)];
#pragma unroll
      for (int n = 0; n < 4; ++n)
        bf[n] = *(const bf16x8*)&Bs[(wc * 64 + n * 16 + llo) * 64 + ((kk * 32 + lhi * 8) ^ swl)];
#pragma unroll
      for (int m = 0; m < 4; ++m)
#pragma unroll
        for (int n = 0; n < 4; ++n)
          acc[m][n] = __builtin_amdgcn_mfma_f32_16x16x32_bf16(af[m], bf[n], acc[m][n], 0, 0, 0);
    }
    __syncthreads();
  }

  // epilogue: C/D layout col=lane&15, row=(lane>>4)*4+reg (m89/m91 verified)
  const float* bias = p.bias[z];
  const float scale = p.scale[z];
  const int mode = p.mode[z];
  float bv[4];
#pragma unroll
  for (int n = 0; n < 4; ++n) bv[n] = bias[bn0 + wc * 64 + n * 16 + llo];
#pragma unroll
  for (int m = 0; m < 4; ++m) {
    int rowb = bm0 + wr * 64 + m * 16 + lhi * 4;
#pragma unroll
    for (int n = 0; n < 4; ++n) {
      int col = bn0 + wc * 64 + n * 16 + llo;
#pragma unroll
      for (int r = 0; r < 4; ++r) {
        float v = (acc[m][n][r] + bv[n]) * scale;
        int row = rowb + r;
        if (mode == 0) {
          ((__hip_bfloat16*)p.out[z])[(size_t)row * 1024 + col] = __float2bfloat16(v);
        } else if (mode == 1) {
          ((float*)p.out[z])[(size_t)row * 1024 + col] = v;
        } else {
          int bb = row >> 11, t = row & 2047;     // row = b*2048+t
          int hh = col >> 6, d = col & 63;        // col = h*64+d
          ((__hip_bfloat16*)p.out[z])[((size_t)((bb * 16 + hh) * 64 + d)) * 2048 + t] =
              __float2bfloat16(v);
        }
      }
    }
  }
}

// ---------------- kernel 3: attention (R14/R18 anchor: bias-NT reads + setprio) ------
// grid (32 qt, 16 h, 2 b), 256 thr = 4 waves; wave owns 16 q-rows; s-chunks of 64.
// S^T = mfma(K, Q): lane holds S[t = w*16+llo][s = f*16+lhi*4+r].
// Cache policy: bias staged NT (cold stream-once read). E stored NORMALLY.
// Pipeline: STAGE(it+1) -> vmcnt(12) -> s_barrier -> compute -> lgkmcnt(0) -> s_barrier.
// LDS = 2*(8+8+16) + 8 = 72 KB -> 2 blocks/CU.
__global__ __launch_bounds__(256, 2) void attn_fwd(
    const __hip_bfloat16* __restrict__ qb,   // [B*T,1024] pre-scaled q
    const __hip_bfloat16* __restrict__ kb,   // [B*T,1024]
    const __hip_bfloat16* __restrict__ vT,   // [B*H*64, 2048]  (v transposed)
    const float* __restrict__ bias,          // [B,H,T,T]
    unsigned char* __restrict__ Ebuf,        // [B,H,T,T] fp8 e4m3 of exp(s)/16
    float* __restrict__ invl,                // [B,H,T] 1/l
    __hip_bfloat16* __restrict__ attn)       // [B*T,1024]
{
  __shared__ __hip_bfloat16 Ks[2][64 * 64];  // 16 KB [s][d], swizzled (row&7)<<3
  __shared__ __hip_bfloat16 Vs[2][64 * 64];  // 16 KB [d][s], swizzled (row&7)<<3
  __shared__ float          bS[2][64 * 64];  // 32 KB [t][s], swizzled (row&15)<<2
  __shared__ __hip_bfloat16 Ps[64 * 64];     // 8 KB  [t][s], swizzled (row&7)<<3
  const int tid = threadIdx.x;
  const int l = tid & 63, w = tid >> 6;
  const int lhi = l >> 4, llo = l & 15;
  const int swl = (llo & 7) << 3;
  const int qt = blockIdx.x, h = blockIdx.y, b = blockIdx.z;
  const int t0 = qt * 64;
  const int tl = w * 16 + llo;               // this lane's local q-row (replicated x4 lhi)
  const __hip_bfloat16* kbase = kb + ((size_t)b * 2048) * 1024 + h * 64;
  const __hip_bfloat16* vbase = vT + ((size_t)((b * 16 + h) * 64)) * 2048;
  const float* bbase = bias + (((size_t)(b * 16 + h)) * 2048 + t0) * 2048;
  unsigned char* erow = Ebuf + (((size_t)(b * 16 + h)) * 2048 + t0 + tl) * 2048;

  // Q fragments straight from global (one-time; drained by prologue vmcnt(0))
  bf16x8 qa[2];
#pragma unroll
  for (int kk = 0; kk < 2; ++kk)
    qa[kk] = *(const bf16x8*)&qb[((size_t)(b * 2048 + t0 + tl)) * 1024 +
                                 h * 64 + kk * 32 + lhi * 8];

  f32x4 acc_o[4];
#pragma unroll
  for (int f = 0; f < 4; ++f) acc_o[f] = (f32x4){0.f, 0.f, 0.f, 0.f};
  float lrun = 0.f;

  // 8 gload16 per thread per STAGE: 2 K + 2 V (cached) + 4 bias (NT)
#define STAGE(BUF, S0)                                                         \
  do {                                                                         \
    _Pragma("unroll") for (int j2 = 0; j2 < 2; ++j2) {                         \
      int off = j2 * 2048 + tid * 8;                                           \
      int row = off >> 6, col = off & 63;                                      \
      int cs = col ^ ((row & 7) << 3);                                         \
      gload16(&kbase[(size_t)((S0) + row) * 1024 + cs], &Ks[BUF][off]);        \
      gload16(&vbase[(size_t)row * 2048 + (S0) + cs], &Vs[BUF][off]);          \
    }                                                                          \
    _Pragma("unroll") for (int j2 = 0; j2 < 4; ++j2) {                         \
      int off = j2 * 1024 + tid * 4;                                           \
      int row = off >> 6, col = off & 63;                                      \
      int cs = col ^ ((row & 15) << 2);                                        \
      gload16nt(&bbase[(size_t)row * 2048 + (S0) + cs], &bS[BUF][off]);        \
    }                                                                          \
  } while (0)

  // prologue: stage tile 0, one-time full drain (also covers qa), barrier
  STAGE(0, 0);
  asm volatile("s_waitcnt vmcnt(0)" ::: "memory");
  __builtin_amdgcn_sched_barrier(0);
  __builtin_amdgcn_s_barrier();

  for (int it = 0; it < 32; ++it) {
    const int s0 = it * 64;
    const int cur = it & 1;

    // ---- issue prefetch for it+1 (stays in flight across the barrier) ----
    if (it < 31) {
      STAGE(cur ^ 1, s0 + 64);
      // newer-than-tile-it ops: 8 prefetch + 4 prev-iter E-stores -> allow 12.
      asm volatile("s_waitcnt vmcnt(12)" ::: "memory");
    } else {
      asm volatile("s_waitcnt vmcnt(4)" ::: "memory");
    }
    __builtin_amdgcn_sched_barrier(0);
    __builtin_amdgcn_s_barrier();   // all waves verified their tile-it loads landed

    // ---- S^T = mfma(K, Q): sa[f][r] = S[t=tl][s = s0 + f*16 + lhi*4 + r] ----
    f32x4 sa[4];
#pragma unroll
    for (int f = 0; f < 4; ++f) sa[f] = (f32x4){0.f, 0.f, 0.f, 0.f};
    __builtin_amdgcn_s_setprio(1);
#pragma unroll
    for (int kk = 0; kk < 2; ++kk) {
#pragma unroll
      for (int f = 0; f < 4; ++f) {
        bf16x8 kf = *(const bf16x8*)&Ks[cur][(f * 16 + llo) * 64 +
                                            ((kk * 32 + lhi * 8) ^ swl)];
        sa[f] = __builtin_amdgcn_mfma_f32_16x16x32_bf16(kf, qa[kk], sa[f], 0, 0, 0);
      }
    }
    __builtin_amdgcn_s_setprio(0);
    // ---- bias (vector LDS read) + exp; Ps write b64; E pack direct from regs ----
    float rsum = 0.f;
#pragma unroll
    for (int f = 0; f < 4; ++f) {
      f32x4 bb = *(const f32x4*)&bS[cur][tl * 64 + (((f * 4 + lhi) ^ llo) << 2)];
      float ev[4];
#pragma unroll
      for (int r = 0; r < 4; ++r) {
        ev[r] = __expf(sa[f][r] + bb[r]);
        rsum += ev[r];
      }
      bf16x4 pw;
      pw[0] = f2b(ev[0]); pw[1] = f2b(ev[1]);
      pw[2] = f2b(ev[2]); pw[3] = f2b(ev[3]);
      *(bf16x4*)&Ps[tl * 64 + ((f * 16 + lhi * 4) ^ ((llo & 7) << 3))] = pw;
      int e01 = __builtin_amdgcn_cvt_pk_fp8_f32(ev[0] * 0.0625f, ev[1] * 0.0625f, 0, 0);
      int e = __builtin_amdgcn_cvt_pk_fp8_f32(ev[2] * 0.0625f, ev[3] * 0.0625f, e01, 1);
      *(unsigned int*)&erow[s0 + f * 16 + lhi * 4] = (unsigned int)e;
    }
    // ---- row-sum: row tl is split over the 4 lhi-lanes sharing llo ----
    rsum += __shfl_xor(rsum, 16);
    rsum += __shfl_xor(rsum, 32);
    lrun += rsum;
    // ---- PV: acc_o += P @ V  (A-operand from Ps, same read pattern as before) ----
    __builtin_amdgcn_s_setprio(1);
#pragma unroll
    for (int kk = 0; kk < 2; ++kk) {
      bf16x8 pa = *(const bf16x8*)&Ps[(w * 16 + llo) * 64 + ((kk * 32 + lhi * 8) ^ swl)];
#pragma unroll
      for (int f = 0; f < 4; ++f) {
        bf16x8 vf = *(const bf16x8*)&Vs[cur][(f * 16 + llo) * 64 +
                                            ((kk * 32 + lhi * 8) ^ swl)];
        acc_o[f] = __builtin_amdgcn_mfma_f32_16x16x32_bf16(pa, vf, acc_o[f], 0, 0, 0);
      }
    }
    __builtin_amdgcn_s_setprio(0);
    // ---- buffer-reuse fence: LDS reads done, then barrier (NO vmem drain) ----
    asm volatile("s_waitcnt lgkmcnt(0)" ::: "memory");
    __builtin_amdgcn_sched_barrier(0);
    __builtin_amdgcn_s_barrier();
  }
#undef STAGE

  // lane holds 1/l for row tl (replicated over lhi); output rows need lhi*4+r
  float invs = 1.f / lrun;
  float inv4[4];
#pragma unroll
  for (int r = 0; r < 4; ++r) inv4[r] = __shfl(invs, lhi * 4 + r);
#pragma unroll
  for (int f = 0; f < 4; ++f) {
    int d = f * 16 + llo;
#pragma unroll
    for (int r = 0; r < 4; ++r) {
      int t = t0 + w * 16 + lhi * 4 + r;
      attn[((size_t)(b * 2048 + t)) * 1024 + h * 64 + d] =
          __float2bfloat16(acc_o[f][r] * inv4[r]);
    }
  }
  if (l < 16)
    invl[((size_t)(b * 16 + h)) * 2048 + t0 + w * 16 + l] = invs;
}

// ---------------- kernel 4: avg_weights = sum_h E * inv_l  (the /16 is absorbed) -------
// Plain cached accesses (R17: NT here regressed; Ebuf has an L2-resident tail).
__global__ __launch_bounds__(256) void avgw_k(
    const unsigned char* __restrict__ Ebuf, const float* __restrict__ invl,
    float* __restrict__ outw)
{
  int c = blockIdx.x * 256 + threadIdx.x;   // 0..524287 : (b, t, 16-wide s chunk)
  int b = c >> 18;
  int rem = c & 262143;
  int t = rem >> 7;
  int s0 = (rem & 127) << 4;
  float acc[16];
#pragma unroll
  for (int i = 0; i < 16; ++i) acc[i] = 0.f;
#pragma unroll
  for (int hh = 0; hh < 16; ++hh) {
    float inv = invl[((size_t)(b * 16 + hh)) * 2048 + t];
    uint4 evv = *(const uint4*)&Ebuf[(((size_t)(b * 16 + hh)) * 2048 + t) * 2048 + s0];
    unsigned int dw[4] = {evv.x, evv.y, evv.z, evv.w};
#pragma unroll
    for (int q = 0; q < 4; ++q) {
      acc[q * 4 + 0] += __builtin_amdgcn_cvt_f32_fp8(dw[q], 0) * inv;
      acc[q * 4 + 1] += __builtin_amdgcn_cvt_f32_fp8(dw[q], 1) * inv;
      acc[q * 4 + 2] += __builtin_amdgcn_cvt_f32_fp8(dw[q], 2) * inv;
      acc[q * 4 + 3] += __builtin_amdgcn_cvt_f32_fp8(dw[q], 3) * inv;
    }
  }
  float* o = outw + ((size_t)(b * 2048 + t)) * 2048 + s0;
#pragma unroll
  for (int q = 0; q < 4; ++q)
    *(float4*)(o + q * 4) = make_float4(acc[q * 4], acc[q * 4 + 1], acc[q * 4 + 2], acc[q * 4 + 3]);
}

// ---------------- launch ----------------
extern "C" void kernel_launch(void* const* d_in, const int* in_sizes, int n_in,
                              void* d_out, int out_size, void* d_ws, size_t ws_size,
                              hipStream_t stream) {
  const float* query     = (const float*)d_in[0];
  // d_in[1] (key) and d_in[2] (value) are ignored: reference uses query for all.
  const float* attn_bias = (const float*)d_in[3];
  const float* Wq = (const float*)d_in[4];
  const float* bq = (const float*)d_in[5];
  const float* Wk = (const float*)d_in[6];
  const float* bk = (const float*)d_in[7];
  const float* Wv = (const float*)d_in[8];
  const float* bv = (const float*)d_in[9];
  const float* Wo = (const float*)d_in[10];
  const float* bo = (const float*)d_in[11];
  float* out = (float*)d_out;               // [0,4194304) proj-out, then [.. ) avg weights

  char* ws = (char*)d_ws;                   // ~185 MB total
  __hip_bfloat16* xb   = (__hip_bfloat16*)(ws + 0);
  __hip_bfloat16* wqb  = (__hip_bfloat16*)(ws + 8388608);
  __hip_bfloat16* wkb  = (__hip_bfloat16*)(ws + 10485760);
  __hip_bfloat16* wvb  = (__hip_bfloat16*)(ws + 12582912);
  __hip_bfloat16* wob  = (__hip_bfloat16*)(ws + 14680064);
  __hip_bfloat16* qbf  = (__hip_bfloat16*)(ws + 16777216);
  __hip_bfloat16* kbf  = (__hip_bfloat16*)(ws + 25165824);
  __hip_bfloat16* vTb  = (__hip_bfloat16*)(ws + 33554432);
  __hip_bfloat16* atnb = (__hip_bfloat16*)(ws + 41943040);
  float*          linv = (float*)(ws + 50331648);
  unsigned char*  Ebuf = (unsigned char*)(ws + 50593792);

  convert_f32_bf16<<<8192, 256, 0, stream>>>(query, Wq, Wk, Wv, Wo, xb, wqb, wkb, wvb, wob);

  GemmP gp{};
  gp.A = xb;
  gp.Bw[0] = wqb; gp.Bw[1] = wkb; gp.Bw[2] = wvb;
  gp.bias[0] = bq; gp.bias[1] = bk; gp.bias[2] = bv;
  gp.out[0] = qbf; gp.out[1] = kbf; gp.out[2] = vTb;
  gp.scale[0] = 0.125f; gp.scale[1] = 1.f; gp.scale[2] = 1.f;
  gp.mode[0] = 0; gp.mode[1] = 0; gp.mode[2] = 2;
  gemm_nt<<<dim3(32, 8, 3), 256, 0, stream>>>(gp);

  attn_fwd<<<dim3(32, 16, 2), 256, 0, stream>>>(qbf, kbf, vTb, attn_bias, Ebuf, linv, atnb);

  avgw_k<<<2048, 256, 0, stream>>>(Ebuf, linv, out + 4194304);

  GemmP go{};
  go.A = atnb;
  go.Bw[0] = wob; go.bias[0] = bo; go.out[0] = out;
  go.scale[0] = 1.f; go.mode[0] = 1;
  gemm_nt<<<dim3(32, 8, 1), 256, 0, stream>>>(go);
}